// Round 1
// 238.455 us; speedup vs baseline: 1.0554x; 1.0554x over previous
//
#include <hip/hip_runtime.h>
#include <hip/hip_bf16.h>
#include <math.h>

// Problem constants (fixed shapes from setup_inputs)
#define B_    2
#define N_    2048
#define D_    1024
#define H_    16
#define ENC_  8
#define HD_   64
#define EPS_  1e-5f
#define M_    (B_ * N_)        // 4096 rows for all GEMMs

typedef __bf16 bf16x8 __attribute__((ext_vector_type(8)));
typedef __bf16 bf16x2 __attribute__((ext_vector_type(2)));
typedef float  f32x4  __attribute__((ext_vector_type(4)));

#define MB(x) ((size_t)(x) * 1024 * 1024)

// Async global->LDS 16B copy. HW writes lds_base + lane*16 (wave-uniform LDS
// base); the GLOBAL address is per-lane, so scattered gathers are fine.
__device__ __forceinline__ void gld16(const __bf16* g, __bf16* l) {
    __builtin_amdgcn_global_load_lds(
        (const __attribute__((address_space(1))) void*)g,
        (__attribute__((address_space(3))) void*)l,
        16, 0, 0);
}

// ---------------------------------------------------------------------------
// Shared MFMA GEMM core (m97 structure): C[128x128 tile] = A @ Bt^T.
// 4 waves (2x2), each wave 4x4 16x16x32 MFMAs, global_load_lds staging.
// ---------------------------------------------------------------------------
template <typename OutT>
__device__ __forceinline__ void gemm_core(
    const __bf16* __restrict__ A, const __bf16* __restrict__ Bt,
    OutT* __restrict__ C, int K, int lda, int aoff, int ldc,
    int bm, int bn, __bf16* As, __bf16* Bs)
{
    const int tid  = threadIdx.x;
    const int w    = tid >> 6;
    const int lane = tid & 63;
    const int lrow = lane & 15;
    const int quad = lane >> 4;
    const int wr   = w >> 1;
    const int wc   = w & 1;

    const int sr = lane >> 2;
    const int sc = (lane & 3) * 8;
    const __bf16* Ag0 = A  + (size_t)(bm +      w * 16 + sr) * lda + aoff + sc;
    const __bf16* Ag1 = A  + (size_t)(bm + 64 + w * 16 + sr) * lda + aoff + sc;
    const __bf16* Bg0 = Bt + (size_t)(bn +      w * 16 + sr) * K + sc;
    const __bf16* Bg1 = Bt + (size_t)(bn + 64 + w * 16 + sr) * K + sc;
    __bf16* Al0 = &As[w * 512];
    __bf16* Al1 = &As[2048 + w * 512];
    __bf16* Bl0 = &Bs[w * 512];
    __bf16* Bl1 = &Bs[2048 + w * 512];

    f32x4 acc[4][4];
    #pragma unroll
    for (int i = 0; i < 4; ++i)
        #pragma unroll
        for (int j = 0; j < 4; ++j) acc[i][j] = (f32x4){0.f, 0.f, 0.f, 0.f};

    for (int k0 = 0; k0 < K; k0 += 32) {
        gld16(Ag0 + k0, Al0);
        gld16(Ag1 + k0, Al1);
        gld16(Bg0 + k0, Bl0);
        gld16(Bg1 + k0, Bl1);
        __syncthreads();

        bf16x8 af[4], bf[4];
        #pragma unroll
        for (int rt = 0; rt < 4; ++rt)
            af[rt] = *(const bf16x8*)&As[(wr * 64 + rt * 16 + lrow) * 32 + quad * 8];
        #pragma unroll
        for (int ct = 0; ct < 4; ++ct)
            bf[ct] = *(const bf16x8*)&Bs[(wc * 64 + ct * 16 + lrow) * 32 + quad * 8];

        #pragma unroll
        for (int rt = 0; rt < 4; ++rt)
            #pragma unroll
            for (int ct = 0; ct < 4; ++ct)
                acc[rt][ct] = __builtin_amdgcn_mfma_f32_16x16x32_bf16(
                    af[rt], bf[ct], acc[rt][ct], 0, 0, 0);
        __syncthreads();
    }

    #pragma unroll
    for (int rt = 0; rt < 4; ++rt)
        #pragma unroll
        for (int ct = 0; ct < 4; ++ct)
            #pragma unroll
            for (int r = 0; r < 4; ++r) {
                const int row = bm + wr * 64 + rt * 16 + quad * 4 + r;
                const int col = bn + wc * 64 + ct * 16 + lrow;
                C[(size_t)row * ldc + col] = (OutT)acc[rt][ct][r];
            }
}

// QKV projection GEMM (bf16 out)
__global__ __launch_bounds__(256) void gemm_qkv(
    const __bf16* __restrict__ A, const __bf16* __restrict__ Bt,
    __bf16* __restrict__ C)
{
    __shared__ __bf16 As[128 * 32];
    __shared__ __bf16 Bs[128 * 32];
    gemm_core<__bf16>(A, Bt, C, D_, D_, 0, 3072,
                      blockIdx.y * 128, blockIdx.x * 128, As, Bs);
}

// Merged output projections: bx<8 -> enc (K=1024), bx>=8 -> dec (K=512).
__global__ __launch_bounds__(256) void gemm_out(
    const __bf16* __restrict__ A, const __bf16* __restrict__ Woe,
    const __bf16* __restrict__ Wod, float* __restrict__ Cenc,
    float* __restrict__ Cdec)
{
    __shared__ __bf16 As[128 * 32];
    __shared__ __bf16 Bs[128 * 32];
    const int bx = blockIdx.x;
    if (bx < 8) {
        gemm_core<float>(A, Woe, Cenc, 1024, D_, 0, D_,
                         blockIdx.y * 128, bx * 128, As, Bs);
    } else {
        gemm_core<float>(A, Wod, Cdec, 512, D_, 512, D_,
                         blockIdx.y * 128, (bx - 8) * 128, As, Bs);
    }
}

// ---------------------------------------------------------------------------
__global__ __launch_bounds__(256) void f32_to_bf16(
    const float* __restrict__ src, __bf16* __restrict__ dst)
{
    const size_t i = ((size_t)blockIdx.x * 256 + threadIdx.x) * 8;
    float4 a = *(const float4*)&src[i];
    float4 b = *(const float4*)&src[i + 4];
    bf16x8 o = {(__bf16)a.x, (__bf16)a.y, (__bf16)a.z, (__bf16)a.w,
                (__bf16)b.x, (__bf16)b.y, (__bf16)b.z, (__bf16)b.w};
    *(bf16x8*)&dst[i] = o;
}

// ---------------------------------------------------------------------------
// All 5 weight converts (fp32 W[K][Nn] -> bf16 Wt[Nn][K]) in one launch.
// grid (16, 16, 5); z=4 (Wod, K=512) uses only y<8.
// ---------------------------------------------------------------------------
struct WtArgs {
    const float* W[5];
    __bf16*      Wt[5];
    int          K[5];      // rows of W == inner stride of Wt
    int          nyb[5];    // grid-y blocks used
};

__global__ __launch_bounds__(256) void wt_conv_all(WtArgs a)
{
    const int z = blockIdx.z;
    if (blockIdx.y >= a.nyb[z]) return;
    const float* W  = a.W[z];
    __bf16*      Wt = a.Wt[z];
    const int    K  = a.K[z];

    __shared__ __bf16 t[64][72];
    const int kb = blockIdx.y * 64;
    const int nb = blockIdx.x * 64;
    {
        const int kl = threadIdx.x >> 2;
        const int c0 = (threadIdx.x & 3) * 16;
        const float* src = W + (size_t)(kb + kl) * D_ + nb + c0;
        #pragma unroll
        for (int u = 0; u < 4; ++u) {
            float4 f = *(const float4*)&src[u * 4];
            t[c0 + u * 4 + 0][kl] = (__bf16)f.x;
            t[c0 + u * 4 + 1][kl] = (__bf16)f.y;
            t[c0 + u * 4 + 2][kl] = (__bf16)f.z;
            t[c0 + u * 4 + 3][kl] = (__bf16)f.w;
        }
    }
    __syncthreads();
    {
        const int nl  = threadIdx.x >> 2;
        const int k0c = (threadIdx.x & 3) * 16;
        __bf16* dst = Wt + (size_t)(nb + nl) * K + kb + k0c;
        *(bf16x8*)&dst[0] = *(const bf16x8*)&t[nl][k0c];
        *(bf16x8*)&dst[8] = *(const bf16x8*)&t[nl][k0c + 8];
    }
}

// ---------------------------------------------------------------------------
// Fused RoPE+RMSNorm (q,k) + V transpose, one launch.
// blocks [0,16384): rope path (4 rows/block); [16384,17408): vconv path.
// R10: V^T is written KEY-PERMUTED within each 32-key group:
//   position(k) = 2*(k&15) + (k>>4)   (inverse: k = (p>>1) + 16*(p&1))
// so that attention's P tile can be written as packed bf16x2 (pA,pB pairs
// adjacent) while P/V MFMA fragment indices stay unchanged. Contraction over
// a permuted k is invariant since P and V use the same permutation.
// ---------------------------------------------------------------------------
__global__ __launch_bounds__(256) void rope_vconv(
    const __bf16* __restrict__ qkv,
    const float* __restrict__ cs, const float* __restrict__ sn,
    __bf16* __restrict__ qbf, __bf16* __restrict__ kbf,
    __bf16* __restrict__ vt)
{
    if (blockIdx.x < 16384) {
        const int row  = blockIdx.x * 4 + (threadIdx.x >> 6);  // (b*N+n)*H + h
        const int lane = threadIdx.x & 63;
        const int n    = (row >> 4) & (N_ - 1);
        const int b    = row >> 15;
        const int h    = row & 15;
        const int p    = lane >> 1;

        const float c = cs[n * (HD_ / 2) + p];
        const float s = sn[n * (HD_ / 2) + p];
        const size_t ibase = (size_t)(b * N_ + n) * 3072 + h * HD_ + lane;
        const size_t obase = ((size_t)(b * H_ + h) * N_ + n) * HD_ + lane;
        const bool odd = (lane & 1);

        {
            float val = (float)qkv[ibase];                  // q
            float partner = __shfl_xor(val, 1, 64);
            float r = odd ? fmaf(partner, s, val * c)
                          : (val * c - partner * s);
            float ss = r * r;
            #pragma unroll
            for (int off = 1; off < 64; off <<= 1) ss += __shfl_xor(ss, off, 64);
            qbf[obase] = (__bf16)(r * rsqrtf(ss * (1.0f / 64.0f) + EPS_));
        }
        {
            float val = (float)qkv[ibase + 1024];           // k
            float partner = __shfl_xor(val, 1, 64);
            float r = odd ? fmaf(partner, s, val * c)
                          : (val * c - partner * s);
            float ss = r * r;
            #pragma unroll
            for (int off = 1; off < 64; off <<= 1) ss += __shfl_xor(ss, off, 64);
            kbf[obase] = (__bf16)(r * rsqrtf(ss * (1.0f / 64.0f) + EPS_));
        }
    } else {
        __shared__ __bf16 tile[64][72];
        const int bx = blockIdx.x - 16384;
        const int bh = bx >> 5;
        const int b  = bh >> 4, h = bh & 15;
        const int n0 = (bx & 31) * 64;
        {
            const int nl = threadIdx.x >> 2;
            const int d0 = (threadIdx.x & 3) * 16;
            const __bf16* src =
                qkv + (size_t)(b * N_ + n0 + nl) * 3072 + 2048 + h * HD_ + d0;
            bf16x8 v0 = *(const bf16x8*)&src[0];
            bf16x8 v1 = *(const bf16x8*)&src[8];
            #pragma unroll
            for (int e = 0; e < 8; ++e) {
                tile[d0 + e][nl]     = v0[e];
                tile[d0 + 8 + e][nl] = v1[e];
            }
        }
        __syncthreads();
        {
            const int dl = threadIdx.x >> 2;
            const int nc = (threadIdx.x & 3) * 16;
            __bf16* dst = vt + ((size_t)(bh * HD_ + dl)) * N_ + n0 + nc;
            bf16x8 o0, o1;
            #pragma unroll
            for (int e = 0; e < 8; ++e) {
                const int p0 = nc + e;
                const int p1 = nc + 8 + e;
                o0[e] = tile[dl][(p0 & ~31) + ((p0 & 31) >> 1) + 16 * (p0 & 1)];
                o1[e] = tile[dl][(p1 & ~31) + ((p1 & 31) >> 1) + 16 * (p1 & 1)];
            }
            *(bf16x8*)&dst[0] = o0;
            *(bf16x8*)&dst[8] = o1;
        }
    }
}

// ---------------------------------------------------------------------------
// MFMA flash attention v7 (bf16 in, bf16 out).
// R10 changes vs R9:
//   (a) Work-balanced 1-D grid of 768 blocks (3/CU, all co-resident, all
//       equal length): blocks [0,512) = enc, one qb each (32 tiles);
//       blocks [512,768) = dec, a PAIR (31-p, p) of qbs (33 tiles total).
//       Removes the ~24% dec-drain tail (Occupancy was 26% vs 50% resident).
//   (b) P written to LDS as packed bf16x2 (one v_cvt_pk + ds_write_b32 per
//       row-pair instead of 2 scalar cvts + 2 ds_write_b16), enabled by the
//       key-interleaved V^T layout produced by rope_vconv. Fragment read
//       indices (P and V) are UNCHANGED.
//   K LDS: chunk p = dimchunk*64 + key   (8 dc x 64 keys)
//   V LDS: chunk p = keyoct*64 + dim     (8 ko x 64 dims)  [keys permuted]
// Block = 64 q-rows of one bh (4 waves x 16).
// ---------------------------------------------------------------------------
__global__ __launch_bounds__(256) void attn_mfma(
    const __bf16* __restrict__ qbf, const __bf16* __restrict__ kbf,
    const __bf16* __restrict__ vtbf, __bf16* __restrict__ o)
{
    __shared__ __bf16 Ks[2][4096];       // 8 KB per buffer
    __shared__ __bf16 Vs[2][4096];
    __shared__ __bf16 Plds[4][16][36];   // [wave][qrow][keypos(padded)]

    const int tid  = threadIdx.x;
    const int w    = tid >> 6;
    const int lane = tid & 63;
    const int lrow = lane & 15;
    const int quad = lane >> 4;

    // Work-balanced decomposition
    int bh, nwork, qbs[2];
    if (blockIdx.x < 512) {              // enc: 16 bh x 32 qb
        const int e = blockIdx.x >> 5;
        bh = (e >> 3) * 16 + (e & 7);
        qbs[0] = blockIdx.x & 31;
        qbs[1] = 0;
        nwork = 1;
    } else {                             // dec: 16 bh x 16 pairs
        const int idx = blockIdx.x - 512;
        const int e = idx >> 4;
        bh = (e >> 3) * 16 + 8 + (e & 7);
        const int p = idx & 15;
        qbs[0] = 31 - p;                 // heavy half first
        qbs[1] = p;                      // light half second
        nwork = 2;
    }
    const int b = bh >> 4, h = bh & 15;
    const bool enc = (h < ENC_);
    const bool dec = !enc;

    const __bf16* qbase = qbf  + (size_t)bh * N_ * HD_;
    const __bf16* kbase = kbf  + (size_t)bh * N_ * HD_;
    const __bf16* vbase = vtbf + (size_t)bh * HD_ * N_;

    // Staging (wave w handles chunk groups m = w and m = w+4):
    //   K group m: lane l -> key l, dims [m*8, m*8+8)
    //   V group m: lane l -> dim l, keypos [m*8, m*8+8)
    const __bf16* kg0 = kbase + (size_t)lane * HD_ + w * 8;        // m=w
    const __bf16* kg1 = kbase + (size_t)lane * HD_ + (w + 4) * 8;  // m=w+4
    const __bf16* vg  = vbase + (size_t)lane * N_;

    const f32x4 zero = {0.f, 0.f, 0.f, 0.f};
    const float KSc = 0.125f * 1.4426950408889634f;
    const float KOc = -8.0f  * 1.4426950408889634f;

    for (int wi = 0; wi < nwork; ++wi) {
        const int qb = qbs[wi];
        const int i0 = qb * 64 + w * 16;                 // wave's 16 q-rows
        const int ntiles = enc ? (N_ >> 6) : (qb + 1);

        bf16x8 qf[2];
        #pragma unroll
        for (int kc = 0; kc < 2; ++kc)
            qf[kc] = *(const bf16x8*)
                &qbase[(size_t)(i0 + lrow) * HD_ + kc * 32 + quad * 8];

        f32x4 oacc[4];
        #pragma unroll
        for (int c = 0; c < 4; ++c) oacc[c] = zero;
        float lsum[4] = {};

        auto stage = [&](int t, int bb) {
            const int j0 = t << 6;
            gld16(kg0 + (size_t)j0 * HD_, &Ks[bb][(w)     * 512]);
            gld16(kg1 + (size_t)j0 * HD_, &Ks[bb][(w + 4) * 512]);
            gld16(vg + j0 + w * 8,        &Vs[bb][(w)     * 512]);
            gld16(vg + j0 + (w + 4) * 8,  &Vs[bb][(w + 4) * 512]);
        };

        if (wi) __syncthreads();    // protect Ks/Vs/Plds reuse across items
        stage(0, 0);
        for (int t = 0; t < ntiles; ++t) {
            const int bb = t & 1;
            __syncthreads();            // buf bb staged; prev compute done
            if (t + 1 < ntiles) stage(t + 1, bb ^ 1);

            #pragma unroll
            for (int s = 0; s < 2; ++s) {
                const int jp = (t << 6) + s * 32;   // pass keys [jp, jp+32)

                // K fragments: elem ((kc*4+quad)*64 + s*32 + u*16 + lrow)*8
                bf16x8 kf0 = *(const bf16x8*)&Ks[bb][((quad)     * 64 + s * 32 + lrow) * 8];
                bf16x8 kf1 = *(const bf16x8*)&Ks[bb][((4 + quad) * 64 + s * 32 + lrow) * 8];
                bf16x8 kf2 = *(const bf16x8*)&Ks[bb][((quad)     * 64 + s * 32 + 16 + lrow) * 8];
                bf16x8 kf3 = *(const bf16x8*)&Ks[bb][((4 + quad) * 64 + s * 32 + 16 + lrow) * 8];

                f32x4 s0 = zero, s1 = zero;
                s0 = __builtin_amdgcn_mfma_f32_16x16x32_bf16(qf[0], kf0, s0, 0, 0, 0);
                s0 = __builtin_amdgcn_mfma_f32_16x16x32_bf16(qf[1], kf1, s0, 0, 0, 0);
                s1 = __builtin_amdgcn_mfma_f32_16x16x32_bf16(qf[0], kf2, s1, 0, 0, 0);
                s1 = __builtin_amdgcn_mfma_f32_16x16x32_bf16(qf[1], kf3, s1, 0, 0, 0);

                if (dec && (jp + 31 > i0)) {   // pass can reach above diagonal
                    #pragma unroll
                    for (int r = 0; r < 4; ++r) {
                        const int i  = i0 + quad * 4 + r;
                        float pA = (jp + lrow      <= i) ? exp2f(fmaf(s0[r], KSc, KOc)) : 0.f;
                        float pB = (jp + 16 + lrow <= i) ? exp2f(fmaf(s1[r], KSc, KOc)) : 0.f;
                        lsum[r] += pA + pB;
                        bf16x2 pp = {(__bf16)pA, (__bf16)pB};
                        *(bf16x2*)&Plds[w][quad * 4 + r][2 * lrow] = pp;
                    }
                } else {
                    #pragma unroll
                    for (int r = 0; r < 4; ++r) {
                        float pA = exp2f(fmaf(s0[r], KSc, KOc));
                        float pB = exp2f(fmaf(s1[r], KSc, KOc));
                        lsum[r] += pA + pB;
                        bf16x2 pp = {(__bf16)pA, (__bf16)pB};
                        *(bf16x2*)&Plds[w][quad * 4 + r][2 * lrow] = pp;
                    }
                }

                // V fragments: elem ((s*4+quad)*64 + c*16 + lrow)*8
                // (key positions permuted identically to P's columns)
                bf16x8 vf0 = *(const bf16x8*)&Vs[bb][((s * 4 + quad) * 64 +  0 + lrow) * 8];
                bf16x8 vf1 = *(const bf16x8*)&Vs[bb][((s * 4 + quad) * 64 + 16 + lrow) * 8];
                bf16x8 vf2 = *(const bf16x8*)&Vs[bb][((s * 4 + quad) * 64 + 32 + lrow) * 8];
                bf16x8 vf3 = *(const bf16x8*)&Vs[bb][((s * 4 + quad) * 64 + 48 + lrow) * 8];

                bf16x8 pf = *(const bf16x8*)&Plds[w][lrow][quad * 8];
                oacc[0] = __builtin_amdgcn_mfma_f32_16x16x32_bf16(pf, vf0, oacc[0], 0, 0, 0);
                oacc[1] = __builtin_amdgcn_mfma_f32_16x16x32_bf16(pf, vf1, oacc[1], 0, 0, 0);
                oacc[2] = __builtin_amdgcn_mfma_f32_16x16x32_bf16(pf, vf2, oacc[2], 0, 0, 0);
                oacc[3] = __builtin_amdgcn_mfma_f32_16x16x32_bf16(pf, vf3, oacc[3], 0, 0, 0);
            }
        }

        #pragma unroll
        for (int r = 0; r < 4; ++r) {
            float s = lsum[r];
            s += __shfl_xor(s, 1, 64);
            s += __shfl_xor(s, 2, 64);
            s += __shfl_xor(s, 4, 64);
            s += __shfl_xor(s, 8, 64);
            lsum[r] = 1.0f / s;
        }

        // O (bf16, [4096][1024], col = h*64 + dim); C-layout row=quad*4+r
        #pragma unroll
        for (int c = 0; c < 4; ++c)
            #pragma unroll
            for (int r = 0; r < 4; ++r) {
                const int i = i0 + quad * 4 + r;
                o[(size_t)(b * N_ + i) * D_ + h * HD_ + c * 16 + lrow] =
                    (__bf16)(oacc[c][r] * lsum[r]);
            }
    }
}

// ---------------------------------------------------------------------------
extern "C" void kernel_launch(void* const* d_in, const int* in_sizes, int n_in,
                              void* d_out, int out_size, void* d_ws, size_t ws_size,
                              hipStream_t stream)
{
    const float* x   = (const float*)d_in[0];
    const float* cs  = (const float*)d_in[1];
    const float* sn  = (const float*)d_in[2];
    const float* Wq  = (const float*)d_in[3];
    const float* Wk  = (const float*)d_in[4];
    const float* Wv  = (const float*)d_in[5];
    const float* Woe = (const float*)d_in[6];
    const float* Wod = (const float*)d_in[7];

    float* enc_out = (float*)d_out;
    float* dec_out = enc_out + (size_t)M_ * D_;

    // Workspace (57 MB), stream-ordered aliasing:
    //   [0,8)    xbf      -> reused as vtbf after QKV GEMM
    //   [8,14)   wqkv_t   (3072 x 1024 bf16)
    //   [14,16)  woe_t    (1024 x 1024 bf16)
    //   [16,17)  wod_t    (1024 x 512 bf16)
    //   [17,41)  qkv      (4096 x 3072 bf16) -> reused as obuf
    //   [41,49)  qbf head-major
    //   [49,57)  kbf head-major
    char* ws = (char*)d_ws;
    __bf16* xbf    = (__bf16*)(ws);
    __bf16* wqkv_t = (__bf16*)(ws + MB(8));
    __bf16* woe_t  = (__bf16*)(ws + MB(14));
    __bf16* wod_t  = (__bf16*)(ws + MB(16));
    __bf16* qkv    = (__bf16*)(ws + MB(17));
    __bf16* qbf    = (__bf16*)(ws + MB(41));
    __bf16* kbf    = (__bf16*)(ws + MB(49));
    __bf16* vtbf   = xbf;     // xbf dead after QKV GEMM
    __bf16* obuf   = qkv;     // qkv dead after rope_vconv

    // x convert
    f32_to_bf16<<<(M_ * D_) / (256 * 8), 256, 0, stream>>>(x, xbf);

    // all weight converts in one launch
    WtArgs wa;
    wa.W[0] = Wq;  wa.Wt[0] = wqkv_t;                 wa.K[0] = 1024; wa.nyb[0] = 16;
    wa.W[1] = Wk;  wa.Wt[1] = wqkv_t + 1024 * 1024;   wa.K[1] = 1024; wa.nyb[1] = 16;
    wa.W[2] = Wv;  wa.Wt[2] = wqkv_t + 2048 * 1024;   wa.K[2] = 1024; wa.nyb[2] = 16;
    wa.W[3] = Woe; wa.Wt[3] = woe_t;                  wa.K[3] = 1024; wa.nyb[3] = 16;
    wa.W[4] = Wod; wa.Wt[4] = wod_t;                  wa.K[4] = 512;  wa.nyb[4] = 8;
    wt_conv_all<<<dim3(16, 16, 5), 256, 0, stream>>>(wa);

    // Fused QKV projection (bf16 out)
    gemm_qkv<<<dim3(3072 / 128, M_ / 128), 256, 0, stream>>>(xbf, wqkv_t, qkv);

    // RoPE+RMSNorm + V transpose (key-permuted), one launch
    rope_vconv<<<16384 + 1024, 256, 0, stream>>>(qkv, cs, sn, qbf, kbf, vtbf);

    // Attention: work-balanced 768 blocks (512 enc + 256 dec pairs)
    attn_mfma<<<dim3(768), 256, 0, stream>>>(qbf, kbf, vtbf, obuf);

    // Merged output projections (fp32 out)
    gemm_out<<<dim3(16, M_ / 128), 256, 0, stream>>>(
        obuf, woe_t, wod_t, enc_out, dec_out);
}

// Round 2
// 236.360 us; speedup vs baseline: 1.0648x; 1.0089x over previous
//
#include <hip/hip_runtime.h>
#include <hip/hip_bf16.h>
#include <math.h>

// Problem constants (fixed shapes from setup_inputs)
#define B_    2
#define N_    2048
#define D_    1024
#define H_    16
#define ENC_  8
#define HD_   64
#define EPS_  1e-5f
#define M_    (B_ * N_)        // 4096 rows for all GEMMs

typedef __bf16 bf16x8 __attribute__((ext_vector_type(8)));
typedef __bf16 bf16x2 __attribute__((ext_vector_type(2)));
typedef float  f32x4  __attribute__((ext_vector_type(4)));

#define MB(x) ((size_t)(x) * 1024 * 1024)

// Softmax scale folded into Q at RoPE time: 0.125 * log2(e)
#define KSC_  0.18033688011112042f

// Async global->LDS 16B copy. HW writes lds_base + lane*16 (wave-uniform LDS
// base); the GLOBAL address is per-lane, so scattered gathers are fine.
__device__ __forceinline__ void gld16(const __bf16* g, __bf16* l) {
    __builtin_amdgcn_global_load_lds(
        (const __attribute__((address_space(1))) void*)g,
        (__attribute__((address_space(3))) void*)l,
        16, 0, 0);
}

// ---------------------------------------------------------------------------
// Shared MFMA GEMM core (m97 structure): C[128x128 tile] = A @ Bt^T.
// 4 waves (2x2), each wave 4x4 16x16x32 MFMAs, global_load_lds staging.
// ---------------------------------------------------------------------------
template <typename OutT>
__device__ __forceinline__ void gemm_core(
    const __bf16* __restrict__ A, const __bf16* __restrict__ Bt,
    OutT* __restrict__ C, int K, int lda, int aoff, int ldc,
    int bm, int bn, __bf16* As, __bf16* Bs)
{
    const int tid  = threadIdx.x;
    const int w    = tid >> 6;
    const int lane = tid & 63;
    const int lrow = lane & 15;
    const int quad = lane >> 4;
    const int wr   = w >> 1;
    const int wc   = w & 1;

    const int sr = lane >> 2;
    const int sc = (lane & 3) * 8;
    const __bf16* Ag0 = A  + (size_t)(bm +      w * 16 + sr) * lda + aoff + sc;
    const __bf16* Ag1 = A  + (size_t)(bm + 64 + w * 16 + sr) * lda + aoff + sc;
    const __bf16* Bg0 = Bt + (size_t)(bn +      w * 16 + sr) * K + sc;
    const __bf16* Bg1 = Bt + (size_t)(bn + 64 + w * 16 + sr) * K + sc;
    __bf16* Al0 = &As[w * 512];
    __bf16* Al1 = &As[2048 + w * 512];
    __bf16* Bl0 = &Bs[w * 512];
    __bf16* Bl1 = &Bs[2048 + w * 512];

    f32x4 acc[4][4];
    #pragma unroll
    for (int i = 0; i < 4; ++i)
        #pragma unroll
        for (int j = 0; j < 4; ++j) acc[i][j] = (f32x4){0.f, 0.f, 0.f, 0.f};

    for (int k0 = 0; k0 < K; k0 += 32) {
        gld16(Ag0 + k0, Al0);
        gld16(Ag1 + k0, Al1);
        gld16(Bg0 + k0, Bl0);
        gld16(Bg1 + k0, Bl1);
        __syncthreads();

        bf16x8 af[4], bf[4];
        #pragma unroll
        for (int rt = 0; rt < 4; ++rt)
            af[rt] = *(const bf16x8*)&As[(wr * 64 + rt * 16 + lrow) * 32 + quad * 8];
        #pragma unroll
        for (int ct = 0; ct < 4; ++ct)
            bf[ct] = *(const bf16x8*)&Bs[(wc * 64 + ct * 16 + lrow) * 32 + quad * 8];

        #pragma unroll
        for (int rt = 0; rt < 4; ++rt)
            #pragma unroll
            for (int ct = 0; ct < 4; ++ct)
                acc[rt][ct] = __builtin_amdgcn_mfma_f32_16x16x32_bf16(
                    af[rt], bf[ct], acc[rt][ct], 0, 0, 0);
        __syncthreads();
    }

    #pragma unroll
    for (int rt = 0; rt < 4; ++rt)
        #pragma unroll
        for (int ct = 0; ct < 4; ++ct)
            #pragma unroll
            for (int r = 0; r < 4; ++r) {
                const int row = bm + wr * 64 + rt * 16 + quad * 4 + r;
                const int col = bn + wc * 64 + ct * 16 + lrow;
                C[(size_t)row * ldc + col] = (OutT)acc[rt][ct][r];
            }
}

// QKV projection GEMM (bf16 out)
__global__ __launch_bounds__(256) void gemm_qkv(
    const __bf16* __restrict__ A, const __bf16* __restrict__ Bt,
    __bf16* __restrict__ C)
{
    __shared__ __bf16 As[128 * 32];
    __shared__ __bf16 Bs[128 * 32];
    gemm_core<__bf16>(A, Bt, C, D_, D_, 0, 3072,
                      blockIdx.y * 128, blockIdx.x * 128, As, Bs);
}

// Merged output projections: bx<8 -> enc (K=1024), bx>=8 -> dec (K=512).
__global__ __launch_bounds__(256) void gemm_out(
    const __bf16* __restrict__ A, const __bf16* __restrict__ Woe,
    const __bf16* __restrict__ Wod, float* __restrict__ Cenc,
    float* __restrict__ Cdec)
{
    __shared__ __bf16 As[128 * 32];
    __shared__ __bf16 Bs[128 * 32];
    const int bx = blockIdx.x;
    if (bx < 8) {
        gemm_core<float>(A, Woe, Cenc, 1024, D_, 0, D_,
                         blockIdx.y * 128, bx * 128, As, Bs);
    } else {
        gemm_core<float>(A, Wod, Cdec, 512, D_, 512, D_,
                         blockIdx.y * 128, (bx - 8) * 128, As, Bs);
    }
}

// ---------------------------------------------------------------------------
__global__ __launch_bounds__(256) void f32_to_bf16(
    const float* __restrict__ src, __bf16* __restrict__ dst)
{
    const size_t i = ((size_t)blockIdx.x * 256 + threadIdx.x) * 8;
    float4 a = *(const float4*)&src[i];
    float4 b = *(const float4*)&src[i + 4];
    bf16x8 o = {(__bf16)a.x, (__bf16)a.y, (__bf16)a.z, (__bf16)a.w,
                (__bf16)b.x, (__bf16)b.y, (__bf16)b.z, (__bf16)b.w};
    *(bf16x8*)&dst[i] = o;
}

// ---------------------------------------------------------------------------
// All 5 weight converts (fp32 W[K][Nn] -> bf16 Wt[Nn][K]) in one launch.
// grid (16, 16, 5); z=4 (Wod, K=512) uses only y<8.
// ---------------------------------------------------------------------------
struct WtArgs {
    const float* W[5];
    __bf16*      Wt[5];
    int          K[5];      // rows of W == inner stride of Wt
    int          nyb[5];    // grid-y blocks used
};

__global__ __launch_bounds__(256) void wt_conv_all(WtArgs a)
{
    const int z = blockIdx.z;
    if (blockIdx.y >= a.nyb[z]) return;
    const float* W  = a.W[z];
    __bf16*      Wt = a.Wt[z];
    const int    K  = a.K[z];

    __shared__ __bf16 t[64][72];
    const int kb = blockIdx.y * 64;
    const int nb = blockIdx.x * 64;
    {
        const int kl = threadIdx.x >> 2;
        const int c0 = (threadIdx.x & 3) * 16;
        const float* src = W + (size_t)(kb + kl) * D_ + nb + c0;
        #pragma unroll
        for (int u = 0; u < 4; ++u) {
            float4 f = *(const float4*)&src[u * 4];
            t[c0 + u * 4 + 0][kl] = (__bf16)f.x;
            t[c0 + u * 4 + 1][kl] = (__bf16)f.y;
            t[c0 + u * 4 + 2][kl] = (__bf16)f.z;
            t[c0 + u * 4 + 3][kl] = (__bf16)f.w;
        }
    }
    __syncthreads();
    {
        const int nl  = threadIdx.x >> 2;
        const int k0c = (threadIdx.x & 3) * 16;
        __bf16* dst = Wt + (size_t)(nb + nl) * K + kb + k0c;
        *(bf16x8*)&dst[0] = *(const bf16x8*)&t[nl][k0c];
        *(bf16x8*)&dst[8] = *(const bf16x8*)&t[nl][k0c + 8];
    }
}

// ---------------------------------------------------------------------------
// Fused RoPE+RMSNorm (q,k) + V transpose, one launch.
// blocks [0,16384): rope path (4 rows/block); [16384,17408): vconv path.
// Q is pre-scaled by 0.125*log2e (softmax scale folded in; exp2 in attn then
// needs no fma). V^T is written KEY-PERMUTED within each 32-key group:
//   position(k) = 2*(k&15) + (k>>4)   (inverse: k = (p>>1) + 16*(p&1))
// so attention's P tile can be written as packed bf16x2 while P/V MFMA
// fragment indices stay unchanged (same permutation on both operands).
// ---------------------------------------------------------------------------
__global__ __launch_bounds__(256) void rope_vconv(
    const __bf16* __restrict__ qkv,
    const float* __restrict__ cs, const float* __restrict__ sn,
    __bf16* __restrict__ qbf, __bf16* __restrict__ kbf,
    __bf16* __restrict__ vt)
{
    if (blockIdx.x < 16384) {
        const int row  = blockIdx.x * 4 + (threadIdx.x >> 6);  // (b*N+n)*H + h
        const int lane = threadIdx.x & 63;
        const int n    = (row >> 4) & (N_ - 1);
        const int b    = row >> 15;
        const int h    = row & 15;
        const int p    = lane >> 1;

        const float c = cs[n * (HD_ / 2) + p];
        const float s = sn[n * (HD_ / 2) + p];
        const size_t ibase = (size_t)(b * N_ + n) * 3072 + h * HD_ + lane;
        const size_t obase = ((size_t)(b * H_ + h) * N_ + n) * HD_ + lane;
        const bool odd = (lane & 1);

        {
            float val = (float)qkv[ibase];                  // q
            float partner = __shfl_xor(val, 1, 64);
            float r = odd ? fmaf(partner, s, val * c)
                          : (val * c - partner * s);
            float ss = r * r;
            #pragma unroll
            for (int off = 1; off < 64; off <<= 1) ss += __shfl_xor(ss, off, 64);
            qbf[obase] = (__bf16)(r * rsqrtf(ss * (1.0f / 64.0f) + EPS_) * KSC_);
        }
        {
            float val = (float)qkv[ibase + 1024];           // k
            float partner = __shfl_xor(val, 1, 64);
            float r = odd ? fmaf(partner, s, val * c)
                          : (val * c - partner * s);
            float ss = r * r;
            #pragma unroll
            for (int off = 1; off < 64; off <<= 1) ss += __shfl_xor(ss, off, 64);
            kbf[obase] = (__bf16)(r * rsqrtf(ss * (1.0f / 64.0f) + EPS_));
        }
    } else {
        __shared__ __bf16 tile[64][72];
        const int bx = blockIdx.x - 16384;
        const int bh = bx >> 5;
        const int b  = bh >> 4, h = bh & 15;
        const int n0 = (bx & 31) * 64;
        {
            const int nl = threadIdx.x >> 2;
            const int d0 = (threadIdx.x & 3) * 16;
            const __bf16* src =
                qkv + (size_t)(b * N_ + n0 + nl) * 3072 + 2048 + h * HD_ + d0;
            bf16x8 v0 = *(const bf16x8*)&src[0];
            bf16x8 v1 = *(const bf16x8*)&src[8];
            #pragma unroll
            for (int e = 0; e < 8; ++e) {
                tile[d0 + e][nl]     = v0[e];
                tile[d0 + 8 + e][nl] = v1[e];
            }
        }
        __syncthreads();
        {
            const int dl = threadIdx.x >> 2;
            const int nc = (threadIdx.x & 3) * 16;
            __bf16* dst = vt + ((size_t)(bh * HD_ + dl)) * N_ + n0 + nc;
            bf16x8 o0, o1;
            #pragma unroll
            for (int e = 0; e < 8; ++e) {
                const int p0 = nc + e;
                const int p1 = nc + 8 + e;
                o0[e] = tile[dl][(p0 & ~31) + ((p0 & 31) >> 1) + 16 * (p0 & 1)];
                o1[e] = tile[dl][(p1 & ~31) + ((p1 & 31) >> 1) + 16 * (p1 & 1)];
            }
            *(bf16x8*)&dst[0] = o0;
            *(bf16x8*)&dst[8] = o1;
        }
    }
}

// ---------------------------------------------------------------------------
// MFMA flash attention v8 (bf16 in, bf16 out).
// R11 changes vs R10:
//   (a) XCD-keyed block order. Linear block id % 8 selects the XCD; make the
//       HEAD the low field so all blocks of a bh land on ONE XCD (R10 spread
//       them across all 8 -> 7x K/V refetch, FETCH 12->83 MB):
//         enc: id = qb*16 + e        (16%8==0 -> XCD = e%8)
//         dec: id = 512 + p*16 + d   (512%8==0 -> XCD = d%8)
//       Per XCD: 2 enc bh + 2 dec bh = 2 MB K/V, fits 4 MB L2.
//   (b) Softmax scale pre-folded into Q (rope) and -8 offset dropped
//       (|score*0.125| <= 8 since ||q||=||k||=8 after RMSNorm -> P <= e^8,
//       safe in bf16); exp2f(s) with no fma.
//   K LDS: chunk p = dimchunk*64 + key   (8 dc x 64 keys)
//   V LDS: chunk p = keyoct*64 + dim     (8 ko x 64 dims)  [keys permuted]
// Block = 64 q-rows of one bh (4 waves x 16); grid 768 (512 enc + 256 dec
// pairs), work-balanced (~33 tiles each).
// ---------------------------------------------------------------------------
__global__ __launch_bounds__(256) void attn_mfma(
    const __bf16* __restrict__ qbf, const __bf16* __restrict__ kbf,
    const __bf16* __restrict__ vtbf, __bf16* __restrict__ o)
{
    __shared__ __bf16 Ks[2][4096];       // 8 KB per buffer
    __shared__ __bf16 Vs[2][4096];
    __shared__ __bf16 Plds[4][16][36];   // [wave][qrow][keypos(padded)]

    const int tid  = threadIdx.x;
    const int w    = tid >> 6;
    const int lane = tid & 63;
    const int lrow = lane & 15;
    const int quad = lane >> 4;

    // Work-balanced, XCD-keyed decomposition
    int bh, nwork, qbs[2];
    if (blockIdx.x < 512) {              // enc: id = qb*16 + e
        const int e = blockIdx.x & 15;
        bh = (e >> 3) * 16 + (e & 7);
        qbs[0] = blockIdx.x >> 4;
        qbs[1] = 0;
        nwork = 1;
    } else {                             // dec: id = 512 + p*16 + d
        const int idx = blockIdx.x - 512;
        const int d = idx & 15;
        bh = (d >> 3) * 16 + 8 + (d & 7);
        const int p = idx >> 4;
        qbs[0] = 31 - p;                 // heavy half first
        qbs[1] = p;                      // light half second
        nwork = 2;
    }
    const int b = bh >> 4, h = bh & 15;
    const bool enc = (h < ENC_);
    const bool dec = !enc;

    const __bf16* qbase = qbf  + (size_t)bh * N_ * HD_;
    const __bf16* kbase = kbf  + (size_t)bh * N_ * HD_;
    const __bf16* vbase = vtbf + (size_t)bh * HD_ * N_;

    // Staging (wave w handles chunk groups m = w and m = w+4):
    //   K group m: lane l -> key l, dims [m*8, m*8+8)
    //   V group m: lane l -> dim l, keypos [m*8, m*8+8)
    const __bf16* kg0 = kbase + (size_t)lane * HD_ + w * 8;        // m=w
    const __bf16* kg1 = kbase + (size_t)lane * HD_ + (w + 4) * 8;  // m=w+4
    const __bf16* vg  = vbase + (size_t)lane * N_;

    const f32x4 zero = {0.f, 0.f, 0.f, 0.f};

    for (int wi = 0; wi < nwork; ++wi) {
        const int qb = qbs[wi];
        const int i0 = qb * 64 + w * 16;                 // wave's 16 q-rows
        const int ntiles = enc ? (N_ >> 6) : (qb + 1);

        bf16x8 qf[2];
        #pragma unroll
        for (int kc = 0; kc < 2; ++kc)
            qf[kc] = *(const bf16x8*)
                &qbase[(size_t)(i0 + lrow) * HD_ + kc * 32 + quad * 8];

        f32x4 oacc[4];
        #pragma unroll
        for (int c = 0; c < 4; ++c) oacc[c] = zero;
        float lsum[4] = {};

        auto stage = [&](int t, int bb) {
            const int j0 = t << 6;
            gld16(kg0 + (size_t)j0 * HD_, &Ks[bb][(w)     * 512]);
            gld16(kg1 + (size_t)j0 * HD_, &Ks[bb][(w + 4) * 512]);
            gld16(vg + j0 + w * 8,        &Vs[bb][(w)     * 512]);
            gld16(vg + j0 + (w + 4) * 8,  &Vs[bb][(w + 4) * 512]);
        };

        if (wi) __syncthreads();    // protect Ks/Vs/Plds reuse across items
        stage(0, 0);
        for (int t = 0; t < ntiles; ++t) {
            const int bb = t & 1;
            __syncthreads();            // buf bb staged; prev compute done
            if (t + 1 < ntiles) stage(t + 1, bb ^ 1);

            #pragma unroll
            for (int s = 0; s < 2; ++s) {
                const int jp = (t << 6) + s * 32;   // pass keys [jp, jp+32)

                // K fragments: elem ((kc*4+quad)*64 + s*32 + u*16 + lrow)*8
                bf16x8 kf0 = *(const bf16x8*)&Ks[bb][((quad)     * 64 + s * 32 + lrow) * 8];
                bf16x8 kf1 = *(const bf16x8*)&Ks[bb][((4 + quad) * 64 + s * 32 + lrow) * 8];
                bf16x8 kf2 = *(const bf16x8*)&Ks[bb][((quad)     * 64 + s * 32 + 16 + lrow) * 8];
                bf16x8 kf3 = *(const bf16x8*)&Ks[bb][((4 + quad) * 64 + s * 32 + 16 + lrow) * 8];

                f32x4 s0 = zero, s1 = zero;
                s0 = __builtin_amdgcn_mfma_f32_16x16x32_bf16(qf[0], kf0, s0, 0, 0, 0);
                s0 = __builtin_amdgcn_mfma_f32_16x16x32_bf16(qf[1], kf1, s0, 0, 0, 0);
                s1 = __builtin_amdgcn_mfma_f32_16x16x32_bf16(qf[0], kf2, s1, 0, 0, 0);
                s1 = __builtin_amdgcn_mfma_f32_16x16x32_bf16(qf[1], kf3, s1, 0, 0, 0);

                if (dec && (jp + 31 > i0)) {   // pass can reach above diagonal
                    #pragma unroll
                    for (int r = 0; r < 4; ++r) {
                        const int i  = i0 + quad * 4 + r;
                        float pA = (jp + lrow      <= i) ? exp2f(s0[r]) : 0.f;
                        float pB = (jp + 16 + lrow <= i) ? exp2f(s1[r]) : 0.f;
                        lsum[r] += pA + pB;
                        bf16x2 pp = {(__bf16)pA, (__bf16)pB};
                        *(bf16x2*)&Plds[w][quad * 4 + r][2 * lrow] = pp;
                    }
                } else {
                    #pragma unroll
                    for (int r = 0; r < 4; ++r) {
                        float pA = exp2f(s0[r]);
                        float pB = exp2f(s1[r]);
                        lsum[r] += pA + pB;
                        bf16x2 pp = {(__bf16)pA, (__bf16)pB};
                        *(bf16x2*)&Plds[w][quad * 4 + r][2 * lrow] = pp;
                    }
                }

                // V fragments: elem ((s*4+quad)*64 + c*16 + lrow)*8
                // (key positions permuted identically to P's columns)
                bf16x8 vf0 = *(const bf16x8*)&Vs[bb][((s * 4 + quad) * 64 +  0 + lrow) * 8];
                bf16x8 vf1 = *(const bf16x8*)&Vs[bb][((s * 4 + quad) * 64 + 16 + lrow) * 8];
                bf16x8 vf2 = *(const bf16x8*)&Vs[bb][((s * 4 + quad) * 64 + 32 + lrow) * 8];
                bf16x8 vf3 = *(const bf16x8*)&Vs[bb][((s * 4 + quad) * 64 + 48 + lrow) * 8];

                bf16x8 pf = *(const bf16x8*)&Plds[w][lrow][quad * 8];
                oacc[0] = __builtin_amdgcn_mfma_f32_16x16x32_bf16(pf, vf0, oacc[0], 0, 0, 0);
                oacc[1] = __builtin_amdgcn_mfma_f32_16x16x32_bf16(pf, vf1, oacc[1], 0, 0, 0);
                oacc[2] = __builtin_amdgcn_mfma_f32_16x16x32_bf16(pf, vf2, oacc[2], 0, 0, 0);
                oacc[3] = __builtin_amdgcn_mfma_f32_16x16x32_bf16(pf, vf3, oacc[3], 0, 0, 0);
            }
        }

        #pragma unroll
        for (int r = 0; r < 4; ++r) {
            float s = lsum[r];
            s += __shfl_xor(s, 1, 64);
            s += __shfl_xor(s, 2, 64);
            s += __shfl_xor(s, 4, 64);
            s += __shfl_xor(s, 8, 64);
            lsum[r] = 1.0f / s;
        }

        // O (bf16, [4096][1024], col = h*64 + dim); C-layout row=quad*4+r
        #pragma unroll
        for (int c = 0; c < 4; ++c)
            #pragma unroll
            for (int r = 0; r < 4; ++r) {
                const int i = i0 + quad * 4 + r;
                o[(size_t)(b * N_ + i) * D_ + h * HD_ + c * 16 + lrow] =
                    (__bf16)(oacc[c][r] * lsum[r]);
            }
    }
}

// ---------------------------------------------------------------------------
extern "C" void kernel_launch(void* const* d_in, const int* in_sizes, int n_in,
                              void* d_out, int out_size, void* d_ws, size_t ws_size,
                              hipStream_t stream)
{
    const float* x   = (const float*)d_in[0];
    const float* cs  = (const float*)d_in[1];
    const float* sn  = (const float*)d_in[2];
    const float* Wq  = (const float*)d_in[3];
    const float* Wk  = (const float*)d_in[4];
    const float* Wv  = (const float*)d_in[5];
    const float* Woe = (const float*)d_in[6];
    const float* Wod = (const float*)d_in[7];

    float* enc_out = (float*)d_out;
    float* dec_out = enc_out + (size_t)M_ * D_;

    // Workspace (57 MB), stream-ordered aliasing:
    //   [0,8)    xbf      -> reused as vtbf after QKV GEMM
    //   [8,14)   wqkv_t   (3072 x 1024 bf16)
    //   [14,16)  woe_t    (1024 x 1024 bf16)
    //   [16,17)  wod_t    (1024 x 512 bf16)
    //   [17,41)  qkv      (4096 x 3072 bf16) -> reused as obuf
    //   [41,49)  qbf head-major
    //   [49,57)  kbf head-major
    char* ws = (char*)d_ws;
    __bf16* xbf    = (__bf16*)(ws);
    __bf16* wqkv_t = (__bf16*)(ws + MB(8));
    __bf16* woe_t  = (__bf16*)(ws + MB(14));
    __bf16* wod_t  = (__bf16*)(ws + MB(16));
    __bf16* qkv    = (__bf16*)(ws + MB(17));
    __bf16* qbf    = (__bf16*)(ws + MB(41));
    __bf16* kbf    = (__bf16*)(ws + MB(49));
    __bf16* vtbf   = xbf;     // xbf dead after QKV GEMM
    __bf16* obuf   = qkv;     // qkv dead after rope_vconv

    // x convert
    f32_to_bf16<<<(M_ * D_) / (256 * 8), 256, 0, stream>>>(x, xbf);

    // all weight converts in one launch
    WtArgs wa;
    wa.W[0] = Wq;  wa.Wt[0] = wqkv_t;                 wa.K[0] = 1024; wa.nyb[0] = 16;
    wa.W[1] = Wk;  wa.Wt[1] = wqkv_t + 1024 * 1024;   wa.K[1] = 1024; wa.nyb[1] = 16;
    wa.W[2] = Wv;  wa.Wt[2] = wqkv_t + 2048 * 1024;   wa.K[2] = 1024; wa.nyb[2] = 16;
    wa.W[3] = Woe; wa.Wt[3] = woe_t;                  wa.K[3] = 1024; wa.nyb[3] = 16;
    wa.W[4] = Wod; wa.Wt[4] = wod_t;                  wa.K[4] = 512;  wa.nyb[4] = 8;
    wt_conv_all<<<dim3(16, 16, 5), 256, 0, stream>>>(wa);

    // Fused QKV projection (bf16 out)
    gemm_qkv<<<dim3(3072 / 128, M_ / 128), 256, 0, stream>>>(xbf, wqkv_t, qkv);

    // RoPE+RMSNorm (Q pre-scaled) + V transpose (key-permuted), one launch
    rope_vconv<<<16384 + 1024, 256, 0, stream>>>(qkv, cs, sn, qbf, kbf, vtbf);

    // Attention: 768 XCD-keyed, work-balanced blocks
    attn_mfma<<<dim3(768), 256, 0, stream>>>(qbf, kbf, vtbf, obuf);

    // Merged output projections (fp32 out)
    gemm_out<<<dim3(16, M_ / 128), 256, 0, stream>>>(
        obuf, woe_t, wod_t, enc_out, dec_out);
}